// Round 12
// baseline (31.403 us; speedup 1.0000x reference)
//
#include <hip/hip_runtime.h>

#define E  9
#define B_ 8
#define H_ 224
#define W_ 224
#define C_ 32
#define TH 7                        // rows per thread
#define WT 16                       // w pixels per block (256 thr / 16 lanes-per-pixel)
#define STRIPS (H_ / TH)            // 32
#define WTILES (W_ / WT)            // 14
#define NBLK (B_ * STRIPS * WTILES) // 3584 = 14/CU, divisible by 8

typedef float v2f __attribute__((ext_vector_type(2)));

__global__ __launch_bounds__(256, 3) void fm_main(const float* __restrict__ inp,
                                                  const float* __restrict__ kern,
                                                  const float* __restrict__ mask,
                                                  float* __restrict__ out) {
    int t = threadIdx.x;

    // Bijective XCD-chunk swizzle (448 blocks per XCD).
    int bid = blockIdx.x;
    int swz = (bid & 7) * (NBLK / 8) + (bid >> 3);
    int bw  = swz % WTILES;
    int t2  = swz / WTILES;
    int hs  = (t2 % STRIPS) * TH;   // strip start row
    int b   = t2 / STRIPS;

    int cp = (t & 15) << 1;         // channel pair: 0,2,...,30
    int wl = t >> 4;                // 0..15
    int w  = bw * WT + wl;

    // ---- Barrier-free, LDS-free prep: 2 channels/thread => 16 lanes cover
    // all 32 channels; shfl_xor 1,2,4,8 gives every lane the global max.
    // Coeff live-set is now only 36 VGPRs (cm+ck as v2f), small enough for
    // the allocator to keep register-resident across the row loop (the 4ch
    // version provably re-loaded+renormalized every row: VGPR=72 < live set).
    v2f cm[E], ck[E];
    float mx = 0.0f;
#pragma unroll
    for (int e = 0; e < E; ++e) {
        v2f mv = *reinterpret_cast<const v2f*>(mask + e * C_ + cp);
        v2f kv = *reinterpret_cast<const v2f*>(kern + e * C_ + cp);
        mx = fmaxf(mx, fmaxf(fabsf(mv.x), fabsf(mv.y)));
        cm[e] = mv; ck[e] = kv;
    }
    mx = fmaxf(mx, __shfl_xor(mx, 1));
    mx = fmaxf(mx, __shfl_xor(mx, 2));
    mx = fmaxf(mx, __shfl_xor(mx, 4));
    mx = fmaxf(mx, __shfl_xor(mx, 8));
    float inv = 1.0f / (mx + 1e-6f);
#pragma unroll
    for (int e = 0; e < E; ++e) {
        cm[e].x = fabsf(cm[e].x) * inv;   // abs folds as src modifier
        cm[e].y = fabsf(cm[e].y) * inv;
    }
#pragma unroll
    for (int e = 0; e < E; ++e)
        asm volatile("" :: "v"(cm[e]), "v"(ck[e]));   // pin before loop

    const float* base = inp + (((size_t)b * H_ * W_ + w) * C_) + cp;
    bool wm = (w > 0);
    bool wp = (w < W_ - 1);

    const v2f z2 = {0.f, 0.f};

    v2f win[3][3];   // [ring slot][x-offset -1,0,+1]

    auto ld3 = [&](int hh, v2f* r) {
        if ((unsigned)hh < (unsigned)H_) {   // block-uniform branch
            const float* p = base + (size_t)hh * (W_ * C_);
            r[0] = wm ? *reinterpret_cast<const v2f*>(p - C_) : z2;
            r[1] = *reinterpret_cast<const v2f*>(p);
            r[2] = wp ? *reinterpret_cast<const v2f*>(p + C_) : z2;
        } else {
            r[0] = z2; r[1] = z2; r[2] = z2;
        }
    };

    ld3(hs - 1, win[0]);
    ld3(hs,     win[1]);

    const float inv9 = 1.0f / 9.0f;

#pragma unroll
    for (int s = 0; s < TH; ++s) {
        ld3(hs + s + 1, win[(s + 2) % 3]);

        const v2f* rm1 = win[(s + 0) % 3];   // row h-1
        const v2f* r0  = win[(s + 1) % 3];   // row h
        const v2f* rp1 = win[(s + 2) % 3];   // row h+1

        // tap order: e=0 center, then (y,x) raster skipping center
        v2f taps[E];
        taps[0] = r0[1];
        taps[1] = rm1[0]; taps[2] = rm1[1]; taps[3] = rm1[2];
        taps[4] = r0[0];  taps[5] = r0[2];
        taps[6] = rp1[0]; taps[7] = rp1[1]; taps[8] = rp1[2];

        float dA[E], dB[E];
        float n0 = 0.f, n1 = 0.f, sm0 = 0.f, sm1 = 0.f;
#pragma unroll
        for (int e = 0; e < E; ++e) {
            float d0 = fmaf(taps[e].x, cm[e].x, -ck[e].x);
            float d1 = fmaf(taps[e].y, cm[e].y, -ck[e].y);
            dA[e] = d0; dB[e] = d1;
            n0 += fabsf(d0); n1 += fabsf(d1);
            sm0 += d0; sm1 += d1;
        }
        float nm0 = sm0 * (-inv9), nm1 = sm1 * (-inv9);
        float v0 = 0.f, v1 = 0.f;
#pragma unroll
        for (int e = 0; e < E; ++e) {
            v0 += fabsf(fabsf(dA[e]) + nm0);
            v1 += fabsf(fabsf(dB[e]) + nm1);
        }

        v2f o;
        o.x = fmaf(v0, -inv9, 1.0f) * fmaf(n0, -inv9, 1.0f);
        o.y = fmaf(v1, -inv9, 1.0f) * fmaf(n1, -inv9, 1.0f);

        // Output is write-once/never-read: non-temporal bypasses L2/L3.
        float* op = out + (((size_t)b * H_ + (hs + s)) * W_ + w) * C_ + cp;
        __builtin_nontemporal_store(o, reinterpret_cast<v2f*>(op));
    }
}

extern "C" void kernel_launch(void* const* d_in, const int* in_sizes, int n_in,
                              void* d_out, int out_size, void* d_ws, size_t ws_size,
                              hipStream_t stream) {
    const float* inp  = (const float*)d_in[0];
    const float* kern = (const float*)d_in[1];
    const float* mask = (const float*)d_in[2];
    float* out = (float*)d_out;

    fm_main<<<NBLK, 256, 0, stream>>>(inp, kern, mask, out);
}

// Round 13
// 29.760 us; speedup vs baseline: 1.0552x; 1.0552x over previous
//
#include <hip/hip_runtime.h>

#define E  9
#define B_ 8
#define H_ 224
#define W_ 224
#define C_ 32
#define TH 7                        // 224/7=32 strips -> 1792 blocks = exactly 7/CU
#define WT 32                       // w pixels per block
#define STRIPS (H_ / TH)            // 32
#define WTILES (W_ / WT)            // 7
#define NBLK (B_ * STRIPS * WTILES) // 1792 (one batch image per XCD after swizzle)

typedef float v4f __attribute__((ext_vector_type(4)));

__global__ __launch_bounds__(256, 3) void fm_main(const float* __restrict__ inp,
                                                  const float* __restrict__ kern,
                                                  const float* __restrict__ mask,
                                                  float* __restrict__ out) {
    int t = threadIdx.x;

    // Bijective XCD-chunk swizzle: each XCD gets one batch image (224 blocks).
    int bid = blockIdx.x;
    int swz = (bid & 7) * (NBLK / 8) + (bid >> 3);
    int bw  = swz % WTILES;
    int t2  = swz / WTILES;
    int hs  = (t2 % STRIPS) * TH;   // strip start row
    int b   = t2 / STRIPS;

    int cq = (t & 7) << 2;          // channel quad: 0,4,...,28
    int wl = t >> 3;                // 0..31
    int w  = bw * WT + wl;

    // ---- Barrier-free, LDS-free prep (lanes 0..7 cover all 32 channels).
    v4f cm[E], ck[E];
    float mx = 0.0f;
#pragma unroll
    for (int e = 0; e < E; ++e) {
        v4f mv = *reinterpret_cast<const v4f*>(mask + e * C_ + cq);
        v4f kv = *reinterpret_cast<const v4f*>(kern + e * C_ + cq);
        mx = fmaxf(mx, fmaxf(fmaxf(fabsf(mv.x), fabsf(mv.y)),
                             fmaxf(fabsf(mv.z), fabsf(mv.w))));
        cm[e] = mv; ck[e] = kv;
    }
    mx = fmaxf(mx, __shfl_xor(mx, 1));
    mx = fmaxf(mx, __shfl_xor(mx, 2));
    mx = fmaxf(mx, __shfl_xor(mx, 4));
    float inv = 1.0f / (mx + 1e-6f);
#pragma unroll
    for (int e = 0; e < E; ++e) {
        cm[e].x = fabsf(cm[e].x) * inv;
        cm[e].y = fabsf(cm[e].y) * inv;
        cm[e].z = fabsf(cm[e].z) * inv;
        cm[e].w = fabsf(cm[e].w) * inv;
    }
    // "+v" = asm OUTPUT: value is opaque downstream, CANNOT be rematerialized
    // (R9-R11's input-only pin left it rematerializable -> reload+renorm every
    //  row, VGPR stuck at 40-72). This forces 72 coeff VGPRs to stay live.
#pragma unroll
    for (int e = 0; e < E; ++e)
        asm volatile("" : "+v"(cm[e]), "+v"(ck[e]));

    const float* base = inp + (((size_t)b * H_ * W_ + w) * C_) + cq;
    bool wm = (w > 0);
    bool wp = (w < W_ - 1);

    const v4f z4 = {0.f, 0.f, 0.f, 0.f};

    v4f win[3][3];   // [ring slot][x-offset -1,0,+1]

    auto ld3 = [&](int hh, v4f* r) {
        if ((unsigned)hh < (unsigned)H_) {   // block-uniform branch
            const float* p = base + (size_t)hh * (W_ * C_);
            r[0] = wm ? *reinterpret_cast<const v4f*>(p - C_) : z4;
            r[1] = *reinterpret_cast<const v4f*>(p);
            r[2] = wp ? *reinterpret_cast<const v4f*>(p + C_) : z4;
        } else {
            r[0] = z4; r[1] = z4; r[2] = z4;
        }
    };

    ld3(hs - 1, win[0]);
    ld3(hs,     win[1]);

    const float inv9 = 1.0f / 9.0f;

#pragma unroll
    for (int s = 0; s < TH; ++s) {
        ld3(hs + s + 1, win[(s + 2) % 3]);

        const v4f* rm1 = win[(s + 0) % 3];   // row h-1
        const v4f* r0  = win[(s + 1) % 3];   // row h
        const v4f* rp1 = win[(s + 2) % 3];   // row h+1

        // tap order: e=0 center, then (y,x) raster skipping center
        v4f taps[E];
        taps[0] = r0[1];
        taps[1] = rm1[0]; taps[2] = rm1[1]; taps[3] = rm1[2];
        taps[4] = r0[0];  taps[5] = r0[2];
        taps[6] = rp1[0]; taps[7] = rp1[1]; taps[8] = rp1[2];

        v4f o;

        // ---- channels x,y ----
        {
            float dA[E], dB[E];
            float n0 = 0.f, n1 = 0.f, sm0 = 0.f, sm1 = 0.f;
#pragma unroll
            for (int e = 0; e < E; ++e) {
                float d0 = fmaf(taps[e].x, cm[e].x, -ck[e].x);
                float d1 = fmaf(taps[e].y, cm[e].y, -ck[e].y);
                dA[e] = d0; dB[e] = d1;
                n0 += fabsf(d0); n1 += fabsf(d1);
                sm0 += d0; sm1 += d1;
            }
            float nm0 = sm0 * (-inv9), nm1 = sm1 * (-inv9);
            float v0 = 0.f, v1 = 0.f;
#pragma unroll
            for (int e = 0; e < E; ++e) {
                v0 += fabsf(fabsf(dA[e]) + nm0);
                v1 += fabsf(fabsf(dB[e]) + nm1);
            }
            o.x = fmaf(v0, -inv9, 1.0f) * fmaf(n0, -inv9, 1.0f);
            o.y = fmaf(v1, -inv9, 1.0f) * fmaf(n1, -inv9, 1.0f);
        }
        // ---- channels z,w ----
        {
            float dA[E], dB[E];
            float n0 = 0.f, n1 = 0.f, sm0 = 0.f, sm1 = 0.f;
#pragma unroll
            for (int e = 0; e < E; ++e) {
                float d0 = fmaf(taps[e].z, cm[e].z, -ck[e].z);
                float d1 = fmaf(taps[e].w, cm[e].w, -ck[e].w);
                dA[e] = d0; dB[e] = d1;
                n0 += fabsf(d0); n1 += fabsf(d1);
                sm0 += d0; sm1 += d1;
            }
            float nm0 = sm0 * (-inv9), nm1 = sm1 * (-inv9);
            float v0 = 0.f, v1 = 0.f;
#pragma unroll
            for (int e = 0; e < E; ++e) {
                v0 += fabsf(fabsf(dA[e]) + nm0);
                v1 += fabsf(fabsf(dB[e]) + nm1);
            }
            o.z = fmaf(v0, -inv9, 1.0f) * fmaf(n0, -inv9, 1.0f);
            o.w = fmaf(v1, -inv9, 1.0f) * fmaf(n1, -inv9, 1.0f);
        }

        // Output is write-once/never-read: non-temporal bypasses L2/L3.
        float* op = out + (((size_t)b * H_ + (hs + s)) * W_ + w) * C_ + cq;
        __builtin_nontemporal_store(o, reinterpret_cast<v4f*>(op));
    }
}

extern "C" void kernel_launch(void* const* d_in, const int* in_sizes, int n_in,
                              void* d_out, int out_size, void* d_ws, size_t ws_size,
                              hipStream_t stream) {
    const float* inp  = (const float*)d_in[0];
    const float* kern = (const float*)d_in[1];
    const float* mask = (const float*)d_in[2];
    float* out = (float*)d_out;

    fm_main<<<NBLK, 256, 0, stream>>>(inp, kern, mask, out);
}